// Round 1
// baseline (508.390 us; speedup 1.0000x reference)
//
#include <hip/hip_runtime.h>
#include <hip/hip_bf16.h>

typedef __attribute__((ext_vector_type(8))) __bf16 bf16x8;
typedef __attribute__((ext_vector_type(4))) __bf16 bf16x4;
typedef __attribute__((ext_vector_type(4))) float f32x4;

#define NBATCH 64
#define NSEQ   512
#define DMODEL 1024
#define NHEAD  16
#define DHEAD  64
#define MROWS  (NBATCH * NSEQ)   // 32768

static __device__ __forceinline__ void gload_lds16(const void* gp, void* lp) {
  __builtin_amdgcn_global_load_lds(
      (__attribute__((address_space(1))) const void*)gp,
      (__attribute__((address_space(3))) void*)lp,
      16, 0, 0);
}

// ---------------------------------------------------------------- convert
__global__ void cvt_kernel(const float* __restrict__ in, __bf16* __restrict__ out, int n4) {
  int i = blockIdx.x * blockDim.x + threadIdx.x;
  int stride = gridDim.x * blockDim.x;
  for (; i < n4; i += stride) {
    const float4 v = reinterpret_cast<const float4*>(in)[i];
    bf16x4 o;
    o.x = (__bf16)v.x; o.y = (__bf16)v.y; o.z = (__bf16)v.z; o.w = (__bf16)v.w;
    reinterpret_cast<bf16x4*>(out)[i] = o;
  }
}

// ---------------------------------------------------------------- GEMM (NT: C[m,j] = sum_k A[m,k]*Bw[j,k])
// MODE 0: A=xb[32768,1024], Bw=Wqkv[3072,1024]; epilogue bias+relu+decay,
//         writes qf row-major, kfT/vT transposed [B,H,DHEAD,NSEQ].
// MODE 1: A=attn[32768,1024], Bw=Wo[1024,1024]; epilogue +b_o -> f32 out.
template <int MODE>
__global__ void gemm_kernel(const __bf16* __restrict__ A, const __bf16* __restrict__ Bw,
                            const float* __restrict__ bias0, const float* __restrict__ bias1,
                            const float* __restrict__ bias2,
                            __bf16* __restrict__ outq, __bf16* __restrict__ outkT,
                            __bf16* __restrict__ outvT, float* __restrict__ outf) {
  constexpr int K = 1024;
  __shared__ __bf16 As[128 * 32];
  __shared__ __bf16 Bs[128 * 32];
  const int tid = threadIdx.x;
  const int l = tid & 63;
  const int w = tid >> 6;
  const int wr = w >> 1, wc = w & 1;
  const int bm = blockIdx.y, bn = blockIdx.x;
  const int m0 = bm * 128, j0 = bn * 128;

  f32x4 acc[4][4] = {};

  // staging geometry: LDS tile [128 rows][32 k] bf16, 64B per row, 8192B total.
  // inst i, wave w covers LDS bytes [i*4096 + w*1024, +1024)
  const int fb0 = w * 1024;
  const int fb1 = 4096 + w * 1024;
  const int f0 = fb0 + l * 16, f1 = fb1 + l * 16;
  const size_t ga0 = (size_t)(m0 + (f0 >> 6)) * K + ((f0 & 63) >> 1);
  const size_t ga1 = (size_t)(m0 + (f1 >> 6)) * K + ((f1 & 63) >> 1);
  const size_t gb0 = (size_t)(j0 + (f0 >> 6)) * K + ((f0 & 63) >> 1);
  const size_t gb1 = (size_t)(j0 + (f1 >> 6)) * K + ((f1 & 63) >> 1);

  const int lrow = l & 15, lk = (l >> 4) * 8;

  for (int kk = 0; kk < K; kk += 32) {
    gload_lds16(A + ga0 + kk, (char*)As + fb0);
    gload_lds16(A + ga1 + kk, (char*)As + fb1);
    gload_lds16(Bw + gb0 + kk, (char*)Bs + fb0);
    gload_lds16(Bw + gb1 + kk, (char*)Bs + fb1);
    __syncthreads();
    bf16x8 af[4], bfr[4];
#pragma unroll
    for (int mi = 0; mi < 4; mi++)
      af[mi] = *reinterpret_cast<const bf16x8*>(&As[(wr * 64 + mi * 16 + lrow) * 32 + lk]);
#pragma unroll
    for (int ni = 0; ni < 4; ni++)
      bfr[ni] = *reinterpret_cast<const bf16x8*>(&Bs[(wc * 64 + ni * 16 + lrow) * 32 + lk]);
#pragma unroll
    for (int mi = 0; mi < 4; mi++)
#pragma unroll
      for (int ni = 0; ni < 4; ni++)
        acc[mi][ni] = __builtin_amdgcn_mfma_f32_16x16x32_bf16(af[mi], bfr[ni], acc[mi][ni], 0, 0, 0);
    __syncthreads();
  }

  // ------------- epilogue -------------
  // C fragment: col = l&15, row = (l>>4)*4 + r  (verified m89/m91 mapping)
  if constexpr (MODE == 0) {
    const int sel = j0 >> 10;          // 0=q, 1=k, 2=v (tile never crosses boundary)
    const int jb = j0 & 1023;
    const float* bias = (sel == 0) ? bias0 : ((sel == 1) ? bias1 : bias2);
#pragma unroll
    for (int mi = 0; mi < 4; mi++) {
      const int mbase = m0 + wr * 64 + mi * 16 + ((l >> 4) << 2);
#pragma unroll
      for (int ni = 0; ni < 4; ni++) {
        const int j = jb + wc * 64 + ni * 16 + lrow;
        const float bv_ = bias[j];
        if (sel == 0) {
#pragma unroll
          for (int r = 0; r < 4; r++) {
            const int m = mbase + r;
            float val = acc[mi][ni][r] + bv_;
            val = fmaxf(val, 0.f) * __expf(-(float)(m & (NSEQ - 1)) * (1.0f / NSEQ));
            outq[(size_t)m * DMODEL + j] = (__bf16)val;
          }
        } else {
          const int bidx = mbase >> 9;
          const int n0 = mbase & (NSEQ - 1);
          __bf16* dst = (sel == 1) ? outkT : outvT;
          bf16x4 pk;
#pragma unroll
          for (int r = 0; r < 4; r++) {
            float val = acc[mi][ni][r] + bv_;
            if (sel == 1)
              val = fmaxf(val, 0.f) * __expf(-(float)(n0 + r) * (1.0f / NSEQ));
            pk[r] = (__bf16)val;
          }
          // [B,H,DHEAD,NSEQ]: ((bidx*16 + h)*64 + d)*512 + n,  h=j>>6, d=j&63
          *reinterpret_cast<bf16x4*>(
              &dst[((size_t)((bidx * NHEAD + (j >> 6)) * DHEAD + (j & 63))) * NSEQ + n0]) = pk;
        }
      }
    }
  } else {
#pragma unroll
    for (int mi = 0; mi < 4; mi++) {
      const int mbase = m0 + wr * 64 + mi * 16 + ((l >> 4) << 2);
#pragma unroll
      for (int ni = 0; ni < 4; ni++) {
        const int j = j0 + wc * 64 + ni * 16 + lrow;
        const float bo = bias0[j];
#pragma unroll
        for (int r = 0; r < 4; r++)
          outf[(size_t)(mbase + r) * DMODEL + j] = acc[mi][ni][r] + bo;
      }
    }
  }
}

// ---------------------------------------------------------------- attention core
// one block per (b,h); 256 threads = 4 waves.
__global__ void attn_kernel(const __bf16* __restrict__ qf, const __bf16* __restrict__ kfT,
                            const __bf16* __restrict__ vT, __bf16* __restrict__ attn) {
  const int bh = blockIdx.x;                 // b*16 + h
  const int b = bh >> 4, h = bh & 15;
  const __bf16* kT = kfT + (size_t)bh * DHEAD * NSEQ;
  const __bf16* vTp = vT + (size_t)bh * DHEAD * NSEQ;
  const __bf16* qp = qf + (size_t)b * NSEQ * DMODEL + h * DHEAD;   // row n: qp[n*1024 + d]
  __bf16* op = attn + (size_t)b * NSEQ * DMODEL + h * DHEAD;

  const int tid = threadIdx.x;
  const int l = tid & 63;
  const int w = tid >> 6;
  const int lrow = l & 15, lk = (l >> 4) * 8;

  __shared__ __bf16 KVT[64][88];      // KVT[e][d] = KV[d][e], padded stride (176B, 16B-aligned)
  __shared__ float Ksum[64];
  __shared__ float ksum_part[4][64];
  __shared__ float denom[512];

  // ---- phase 1: KV[d,e] = sum_n kfT[d,n]*vT[e,n]; wave w owns d in [w*16, w*16+16)
  {
    f32x4 kv[4] = {};
    const int arow = w * 16 + lrow;
    for (int kk = 0; kk < NSEQ; kk += 32) {
      bf16x8 a = *reinterpret_cast<const bf16x8*>(&kT[(size_t)arow * NSEQ + kk + lk]);
#pragma unroll
      for (int ni = 0; ni < 4; ni++) {
        bf16x8 bv = *reinterpret_cast<const bf16x8*>(&vTp[(size_t)(ni * 16 + lrow) * NSEQ + kk + lk]);
        kv[ni] = __builtin_amdgcn_mfma_f32_16x16x32_bf16(a, bv, kv[ni], 0, 0, 0);
      }
    }
    // write transposed into LDS (bf16): lane holds col e = ni*16+lrow, rows d0..d0+3
    const int d0 = w * 16 + ((l >> 4) << 2);
#pragma unroll
    for (int ni = 0; ni < 4; ni++) {
      const int e = ni * 16 + lrow;
      bf16x4 pk;
#pragma unroll
      for (int r = 0; r < 4; r++) pk[r] = (__bf16)kv[ni][r];
      *reinterpret_cast<bf16x4*>(&KVT[e][d0]) = pk;
    }
  }

  // ---- Ksum[d] = sum_n kfT[d,n]
  {
    const int d = tid & 63, part = tid >> 6;
    float s = 0.f;
    for (int n = part * 128; n < part * 128 + 128; n += 8) {
      bf16x8 kv8 = *reinterpret_cast<const bf16x8*>(&kT[(size_t)d * NSEQ + n]);
#pragma unroll
      for (int j = 0; j < 8; j++) s += (float)kv8[j];
    }
    ksum_part[part][d] = s;
  }
  __syncthreads();
  if (tid < 64)
    Ksum[tid] = ksum_part[0][tid] + ksum_part[1][tid] + ksum_part[2][tid] + ksum_part[3][tid];
  __syncthreads();

  // ---- denom[n] = qf[n,:] . Ksum + eps
  for (int n = tid; n < NSEQ; n += 256) {
    float s = 0.f;
#pragma unroll
    for (int d = 0; d < DHEAD; d += 8) {
      bf16x8 q8 = *reinterpret_cast<const bf16x8*>(&qp[(size_t)n * DMODEL + d]);
#pragma unroll
      for (int j = 0; j < 8; j++) s += (float)q8[j] * Ksum[d + j];
    }
    denom[n] = s + 1e-6f;
  }
  __syncthreads();

  // ---- phase 3: out[n,e] = (sum_d qf[n,d]*KVT[e,d]) / denom[n]
  for (int t = 0; t < 8; t++) {
    const int nrow = t * 64 + w * 16 + lrow;
    bf16x8 a0 = *reinterpret_cast<const bf16x8*>(&qp[(size_t)nrow * DMODEL + lk]);
    bf16x8 a1 = *reinterpret_cast<const bf16x8*>(&qp[(size_t)nrow * DMODEL + 32 + lk]);
    f32x4 o[4] = {};
#pragma unroll
    for (int ni = 0; ni < 4; ni++) {
      bf16x8 b0 = *reinterpret_cast<const bf16x8*>(&KVT[ni * 16 + lrow][lk]);
      bf16x8 b1 = *reinterpret_cast<const bf16x8*>(&KVT[ni * 16 + lrow][32 + lk]);
      o[ni] = __builtin_amdgcn_mfma_f32_16x16x32_bf16(a0, b0, o[ni], 0, 0, 0);
      o[ni] = __builtin_amdgcn_mfma_f32_16x16x32_bf16(a1, b1, o[ni], 0, 0, 0);
    }
    const int n0 = t * 64 + w * 16 + ((l >> 4) << 2);
#pragma unroll
    for (int ni = 0; ni < 4; ni++) {
      const int e = ni * 16 + lrow;
#pragma unroll
      for (int r = 0; r < 4; r++)
        op[(size_t)(n0 + r) * DMODEL + e] = (__bf16)(o[ni][r] / denom[n0 + r]);
    }
  }
}

// ---------------------------------------------------------------- launch
extern "C" void kernel_launch(void* const* d_in, const int* in_sizes, int n_in,
                              void* d_out, int out_size, void* d_ws, size_t ws_size,
                              hipStream_t stream) {
  (void)in_sizes; (void)n_in; (void)out_size; (void)ws_size;
  const float* x  = (const float*)d_in[0];
  const float* Wq = (const float*)d_in[1];
  const float* bq = (const float*)d_in[2];
  const float* Wk = (const float*)d_in[3];
  const float* bk = (const float*)d_in[4];
  const float* Wv = (const float*)d_in[5];
  const float* bv = (const float*)d_in[6];
  const float* Wo = (const float*)d_in[7];
  const float* bo = (const float*)d_in[8];
  float* out = (float*)d_out;

  char* ws = (char*)d_ws;
  __bf16* xb    = (__bf16*)(ws);                    // 64 MB  (reused as attn output)
  __bf16* qf    = (__bf16*)(ws + 67108864);         // 64 MB
  __bf16* kfT   = (__bf16*)(ws + 134217728);        // 64 MB
  __bf16* vT    = (__bf16*)(ws + 201326592);        // 64 MB
  __bf16* Wqkvb = (__bf16*)(ws + 268435456);        // 6 MB
  __bf16* Wob   = (__bf16*)(ws + 274726912);        // 2 MB
  __bf16* attnb = xb;                               // alias: xb dead after QKV GEMM

  cvt_kernel<<<4096, 256, 0, stream>>>(x, xb, (MROWS * DMODEL) / 4);
  cvt_kernel<<<1024, 256, 0, stream>>>(Wq, Wqkvb,                 (DMODEL * DMODEL) / 4);
  cvt_kernel<<<1024, 256, 0, stream>>>(Wk, Wqkvb + DMODEL * DMODEL,     (DMODEL * DMODEL) / 4);
  cvt_kernel<<<1024, 256, 0, stream>>>(Wv, Wqkvb + 2 * DMODEL * DMODEL, (DMODEL * DMODEL) / 4);
  cvt_kernel<<<1024, 256, 0, stream>>>(Wo, Wob, (DMODEL * DMODEL) / 4);

  gemm_kernel<0><<<dim3(24, 256), 256, 0, stream>>>(xb, Wqkvb, bq, bk, bv,
                                                    qf, kfT, vT, nullptr);
  attn_kernel<<<NBATCH * NHEAD, 256, 0, stream>>>(qf, kfT, vT, attnb);
  gemm_kernel<1><<<dim3(8, 256), 256, 0, stream>>>(attnb, Wob, bo, nullptr, nullptr,
                                                   nullptr, nullptr, nullptr, out);
}

// Round 2
// 450.957 us; speedup vs baseline: 1.1274x; 1.1274x over previous
//
#include <hip/hip_runtime.h>
#include <hip/hip_bf16.h>

typedef __attribute__((ext_vector_type(8))) __bf16 bf16x8;
typedef __attribute__((ext_vector_type(4))) __bf16 bf16x4;
typedef __attribute__((ext_vector_type(4))) float f32x4;

#define NBATCH 64
#define NSEQ   512
#define DMODEL 1024
#define NHEAD  16
#define DHEAD  64
#define MROWS  (NBATCH * NSEQ)   // 32768

static __device__ __forceinline__ void gload_lds16(const void* gp, void* lp) {
  __builtin_amdgcn_global_load_lds(
      (__attribute__((address_space(1))) const void*)gp,
      (__attribute__((address_space(3))) void*)lp,
      16, 0, 0);
}

// ---------------------------------------------------------------- convert
__global__ void cvt_kernel(const float* __restrict__ in, __bf16* __restrict__ out, int n4) {
  int i = blockIdx.x * blockDim.x + threadIdx.x;
  int stride = gridDim.x * blockDim.x;
  for (; i < n4; i += stride) {
    const float4 v = reinterpret_cast<const float4*>(in)[i];
    bf16x4 o;
    o.x = (__bf16)v.x; o.y = (__bf16)v.y; o.z = (__bf16)v.z; o.w = (__bf16)v.w;
    reinterpret_cast<bf16x4*>(out)[i] = o;
  }
}

// ---------------------------------------------------------------- 256x256 8-phase GEMM (NT)
// C[m,j] = sum_k A[m,k]*Bw[j,k], K=1024.
// MODE 0: A=xb, Bw=Wqkv[3072,1024]; epilogue bias+relu+decay -> qf / kfT / vT.
// MODE 1: A=attn, Bw=Wo[1024,1024]; epilogue +b_o -> f32 out.
//
// LDS: 8 panels of 16KB: [buf(2)][mat(2:A,B)][khalf(2)] each [256 rows][32 bf16] (64B rows),
// swizzled L ^= ((L>>7)&3)<<4 (16B granule XOR) => 2 lanes/bank on ds_read_b128 (free).
// Staged via global_load_lds with pre-swizzled global source (rule #21).
// 8 waves: wm = w>>2 (M half of 256), wn = w&3 (64-col slice). acc[8][4] f32x4.
// Phases per K-tile: q0: 12 ds_reads (aK0h0,bK0,aK0h1) + stage Bk1(T+1) | MFMA mh0 x k0
//                    q1: 12 ds_reads (aK1h0,bK1,aK1h1) + stage Ak1(T+1) | MFMA mh1 x k0
//                    q2: stage Ak0(T+2)                                 | MFMA mh0 x k1
//                    q3: stage Bk0(T+2), boundary vmcnt(4)              | MFMA mh1 x k1
// All reads of a panel complete (compiler lgkmcnt) >=1 barrier before any stage targets it.
template <int MODE>
__global__ __launch_bounds__(512, 1)
void gemm256_kernel(const __bf16* __restrict__ A, const __bf16* __restrict__ Bw,
                    const float* __restrict__ bias0, const float* __restrict__ bias1,
                    const float* __restrict__ bias2,
                    __bf16* __restrict__ outq, __bf16* __restrict__ outkT,
                    __bf16* __restrict__ outvT, float* __restrict__ outf) {
  extern __shared__ char smem[];
  constexpr int K = 1024;
  constexpr int NT = K / 64;                 // 16 K-tiles
  constexpr int NBN = (MODE == 0) ? 12 : 4;  // N/256
  constexpr int NWG = 128 * NBN;
  constexpr int CPX = NWG / 8;               // NWG % 8 == 0

  const int raw = blockIdx.x;
  const int wgid = (raw & 7) * CPX + (raw >> 3);   // XCD-chunked swizzle (T1)
  const int bm = wgid / NBN;
  const int bn = wgid - bm * NBN;
  const int m0 = bm * 256, j0 = bn * 256;

  const int tid = threadIdx.x;
  const int l = tid & 63;
  const int w = tid >> 6;
  const int wm = w >> 2, wn = w & 3;
  const int lrow = l & 15, g16 = l >> 4;

  f32x4 acc[8][4] = {};

  // stage one 16KB half-panel: part 0=A k0, 1=A k1, 2=B k0, 3=B k1
  auto stage = [&](int part, int tileIdx) {
    const int mat = part >> 1, kh = part & 1;
    const int buf = tileIdx & 1;
    char* region = smem + (((buf << 2) | (mat << 1) | kh) << 14);
    const __bf16* src = mat ? Bw : A;
    const int rowbase = mat ? j0 : m0;
    const int kk = tileIdx * 64 + kh * 32;
#pragma unroll
    for (int i = 0; i < 2; i++) {
      const int Q = i * 8192 + tid * 16;               // linear LDS dest byte
      const int Ls = Q ^ (((Q >> 7) & 3) << 4);        // inverse-swizzled logical byte
      gload_lds16(src + (size_t)(rowbase + (Ls >> 6)) * K + kk + ((Ls & 63) >> 1),
                  region + Q);
    }
  };

  auto ldfrag = [&](int mat, int kh, int buf, int row) -> bf16x8 {
    const int L = row * 64 + g16 * 16;
    const int phys = L ^ (((row >> 1) & 3) << 4);      // same involution as stage
    return *reinterpret_cast<const bf16x8*>(
        smem + (((buf << 2) | (mat << 1) | kh) << 14) + phys);
  };

  // ---- prologue: T0 fully + T1 {Ak0, Bk0}; wait T0 landed (4 loads in flight)
  stage(0, 0); stage(2, 0); stage(3, 0); stage(1, 0);
  stage(0, 1); stage(2, 1);
  asm volatile("s_waitcnt vmcnt(4)" ::: "memory");
  __builtin_amdgcn_s_barrier();

  const int arow = wm * 128 + lrow;
  const int brow = wn * 64 + lrow;

  for (int T = 0; T < NT; T++) {
    const int buf = T & 1;
    // ---------------- q0 ----------------
    bf16x8 a00[4], bk0[4], a10[4];
#pragma unroll
    for (int mi = 0; mi < 4; mi++) a00[mi] = ldfrag(0, 0, buf, arow + mi * 16);
#pragma unroll
    for (int ni = 0; ni < 4; ni++) bk0[ni] = ldfrag(1, 0, buf, brow + ni * 16);
#pragma unroll
    for (int mi = 0; mi < 4; mi++) a10[mi] = ldfrag(0, 0, buf, arow + 64 + mi * 16);
    if (T + 1 < NT) stage(3, T + 1);
    __builtin_amdgcn_s_barrier();
    __builtin_amdgcn_s_setprio(1);
#pragma unroll
    for (int mi = 0; mi < 4; mi++)
#pragma unroll
      for (int ni = 0; ni < 4; ni++)
        acc[mi][ni] = __builtin_amdgcn_mfma_f32_16x16x32_bf16(a00[mi], bk0[ni], acc[mi][ni], 0, 0, 0);
    __builtin_amdgcn_s_setprio(0);
    __builtin_amdgcn_s_barrier();
    // ---------------- q1 ----------------
    bf16x8 a01[4], bk1[4], a11[4];
#pragma unroll
    for (int mi = 0; mi < 4; mi++) a01[mi] = ldfrag(0, 1, buf, arow + mi * 16);
#pragma unroll
    for (int ni = 0; ni < 4; ni++) bk1[ni] = ldfrag(1, 1, buf, brow + ni * 16);
#pragma unroll
    for (int mi = 0; mi < 4; mi++) a11[mi] = ldfrag(0, 1, buf, arow + 64 + mi * 16);
    if (T + 1 < NT) stage(1, T + 1);
    __builtin_amdgcn_s_barrier();
    __builtin_amdgcn_s_setprio(1);
#pragma unroll
    for (int mi = 0; mi < 4; mi++)
#pragma unroll
      for (int ni = 0; ni < 4; ni++)
        acc[4 + mi][ni] = __builtin_amdgcn_mfma_f32_16x16x32_bf16(a10[mi], bk0[ni], acc[4 + mi][ni], 0, 0, 0);
    __builtin_amdgcn_s_setprio(0);
    __builtin_amdgcn_s_barrier();
    // ---------------- q2 ----------------
    if (T + 2 < NT) stage(0, T + 2);
    __builtin_amdgcn_s_barrier();
    __builtin_amdgcn_s_setprio(1);
#pragma unroll
    for (int mi = 0; mi < 4; mi++)
#pragma unroll
      for (int ni = 0; ni < 4; ni++)
        acc[mi][ni] = __builtin_amdgcn_mfma_f32_16x16x32_bf16(a01[mi], bk1[ni], acc[mi][ni], 0, 0, 0);
    __builtin_amdgcn_s_setprio(0);
    __builtin_amdgcn_s_barrier();
    // ---------------- q3 ----------------
    if (T + 2 < NT) stage(2, T + 2);
    __builtin_amdgcn_s_barrier();
    __builtin_amdgcn_s_setprio(1);
#pragma unroll
    for (int mi = 0; mi < 4; mi++)
#pragma unroll
      for (int ni = 0; ni < 4; ni++)
        acc[4 + mi][ni] = __builtin_amdgcn_mfma_f32_16x16x32_bf16(a11[mi], bk1[ni], acc[4 + mi][ni], 0, 0, 0);
    __builtin_amdgcn_s_setprio(0);
    if (T < NT - 2)       asm volatile("s_waitcnt vmcnt(4)" ::: "memory");
    else if (T == NT - 2) asm volatile("s_waitcnt vmcnt(0)" ::: "memory");
    __builtin_amdgcn_s_barrier();
  }

  // ------------- epilogue (C frag: col = l&15, row = g16*4 + r) -------------
  if constexpr (MODE == 0) {
    const int sel = j0 >> 10;          // 0=q, 1=k, 2=v (256 | 1024 => never crosses)
    const int jb = j0 & 1023;
    const float* bias = (sel == 0) ? bias0 : ((sel == 1) ? bias1 : bias2);
#pragma unroll
    for (int mi = 0; mi < 8; mi++) {
      const int mbase = m0 + wm * 128 + mi * 16 + g16 * 4;
#pragma unroll
      for (int ni = 0; ni < 4; ni++) {
        const int j = jb + wn * 64 + ni * 16 + lrow;
        const float bv_ = bias[j];
        if (sel == 0) {
#pragma unroll
          for (int r = 0; r < 4; r++) {
            const int m = mbase + r;
            float val = acc[mi][ni][r] + bv_;
            val = fmaxf(val, 0.f) * __expf(-(float)(m & (NSEQ - 1)) * (1.0f / NSEQ));
            outq[(size_t)m * DMODEL + j] = (__bf16)val;
          }
        } else {
          const int bidx = mbase >> 9;
          const int n0 = mbase & (NSEQ - 1);
          __bf16* dst = (sel == 1) ? outkT : outvT;
          bf16x4 pk;
#pragma unroll
          for (int r = 0; r < 4; r++) {
            float val = acc[mi][ni][r] + bv_;
            if (sel == 1)
              val = fmaxf(val, 0.f) * __expf(-(float)(n0 + r) * (1.0f / NSEQ));
            pk[r] = (__bf16)val;
          }
          *reinterpret_cast<bf16x4*>(
              &dst[((size_t)((bidx * NHEAD + (j >> 6)) * DHEAD + (j & 63))) * NSEQ + n0]) = pk;
        }
      }
    }
  } else {
#pragma unroll
    for (int mi = 0; mi < 8; mi++) {
      const int mbase = m0 + wm * 128 + mi * 16 + g16 * 4;
#pragma unroll
      for (int ni = 0; ni < 4; ni++) {
        const int j = j0 + wn * 64 + ni * 16 + lrow;
        const float bo = bias0[j];
#pragma unroll
        for (int r = 0; r < 4; r++)
          outf[(size_t)(mbase + r) * DMODEL + j] = acc[mi][ni][r] + bo;
      }
    }
  }
}

// ---------------------------------------------------------------- attention core
// one block per (b,h); 256 threads = 4 waves.
__global__ void attn_kernel(const __bf16* __restrict__ qf, const __bf16* __restrict__ kfT,
                            const __bf16* __restrict__ vT, __bf16* __restrict__ attn) {
  const int bh = blockIdx.x;                 // b*16 + h
  const int b = bh >> 4, h = bh & 15;
  const __bf16* kT = kfT + (size_t)bh * DHEAD * NSEQ;
  const __bf16* vTp = vT + (size_t)bh * DHEAD * NSEQ;
  const __bf16* qp = qf + (size_t)b * NSEQ * DMODEL + h * DHEAD;
  __bf16* op = attn + (size_t)b * NSEQ * DMODEL + h * DHEAD;

  const int tid = threadIdx.x;
  const int l = tid & 63;
  const int w = tid >> 6;
  const int lrow = l & 15, lk = (l >> 4) * 8;

  __shared__ __bf16 KVT[64][88];
  __shared__ float Ksum[64];
  __shared__ float ksum_part[4][64];
  __shared__ float denom[512];

  // ---- KV[d,e] = sum_n kfT[d,n]*vT[e,n]; wave w owns d in [w*16, w*16+16)
  {
    f32x4 kv[4] = {};
    const int arow = w * 16 + lrow;
    for (int kk = 0; kk < NSEQ; kk += 32) {
      bf16x8 a = *reinterpret_cast<const bf16x8*>(&kT[(size_t)arow * NSEQ + kk + lk]);
#pragma unroll
      for (int ni = 0; ni < 4; ni++) {
        bf16x8 bv = *reinterpret_cast<const bf16x8*>(&vTp[(size_t)(ni * 16 + lrow) * NSEQ + kk + lk]);
        kv[ni] = __builtin_amdgcn_mfma_f32_16x16x32_bf16(a, bv, kv[ni], 0, 0, 0);
      }
    }
    const int d0 = w * 16 + ((l >> 4) << 2);
#pragma unroll
    for (int ni = 0; ni < 4; ni++) {
      const int e = ni * 16 + lrow;
      bf16x4 pk;
#pragma unroll
      for (int r = 0; r < 4; r++) pk[r] = (__bf16)kv[ni][r];
      *reinterpret_cast<bf16x4*>(&KVT[e][d0]) = pk;
    }
  }

  // ---- Ksum[d] = sum_n kfT[d,n]
  {
    const int d = tid & 63, part = tid >> 6;
    float s = 0.f;
    for (int n = part * 128; n < part * 128 + 128; n += 8) {
      bf16x8 kv8 = *reinterpret_cast<const bf16x8*>(&kT[(size_t)d * NSEQ + n]);
#pragma unroll
      for (int j = 0; j < 8; j++) s += (float)kv8[j];
    }
    ksum_part[part][d] = s;
  }
  __syncthreads();
  if (tid < 64)
    Ksum[tid] = ksum_part[0][tid] + ksum_part[1][tid] + ksum_part[2][tid] + ksum_part[3][tid];
  __syncthreads();

  // ---- denom[n] = qf[n,:] . Ksum + eps
  for (int n = tid; n < NSEQ; n += 256) {
    float s = 0.f;
#pragma unroll
    for (int d = 0; d < DHEAD; d += 8) {
      bf16x8 q8 = *reinterpret_cast<const bf16x8*>(&qp[(size_t)n * DMODEL + d]);
#pragma unroll
      for (int j = 0; j < 8; j++) s += (float)q8[j] * Ksum[d + j];
    }
    denom[n] = s + 1e-6f;
  }
  __syncthreads();

  // ---- out[n,e] = (sum_d qf[n,d]*KVT[e,d]) / denom[n]
  for (int t = 0; t < 8; t++) {
    const int nrow = t * 64 + w * 16 + lrow;
    bf16x8 a0 = *reinterpret_cast<const bf16x8*>(&qp[(size_t)nrow * DMODEL + lk]);
    bf16x8 a1 = *reinterpret_cast<const bf16x8*>(&qp[(size_t)nrow * DMODEL + 32 + lk]);
    f32x4 o[4] = {};
#pragma unroll
    for (int ni = 0; ni < 4; ni++) {
      bf16x8 b0 = *reinterpret_cast<const bf16x8*>(&KVT[ni * 16 + lrow][lk]);
      bf16x8 b1 = *reinterpret_cast<const bf16x8*>(&KVT[ni * 16 + lrow][32 + lk]);
      o[ni] = __builtin_amdgcn_mfma_f32_16x16x32_bf16(a0, b0, o[ni], 0, 0, 0);
      o[ni] = __builtin_amdgcn_mfma_f32_16x16x32_bf16(a1, b1, o[ni], 0, 0, 0);
    }
    const int n0 = t * 64 + w * 16 + ((l >> 4) << 2);
#pragma unroll
    for (int ni = 0; ni < 4; ni++) {
      const int e = ni * 16 + lrow;
#pragma unroll
      for (int r = 0; r < 4; r++)
        op[(size_t)(n0 + r) * DMODEL + e] = (__bf16)(o[ni][r] / denom[n0 + r]);
    }
  }
}

// ---------------------------------------------------------------- launch
extern "C" void kernel_launch(void* const* d_in, const int* in_sizes, int n_in,
                              void* d_out, int out_size, void* d_ws, size_t ws_size,
                              hipStream_t stream) {
  (void)in_sizes; (void)n_in; (void)out_size; (void)ws_size;
  const float* x  = (const float*)d_in[0];
  const float* Wq = (const float*)d_in[1];
  const float* bq = (const float*)d_in[2];
  const float* Wk = (const float*)d_in[3];
  const float* bk = (const float*)d_in[4];
  const float* Wv = (const float*)d_in[5];
  const float* bv = (const float*)d_in[6];
  const float* Wo = (const float*)d_in[7];
  const float* bo = (const float*)d_in[8];
  float* out = (float*)d_out;

  char* ws = (char*)d_ws;
  __bf16* xb    = (__bf16*)(ws);                    // 64 MB  (reused as attn output)
  __bf16* qf    = (__bf16*)(ws + 67108864);         // 64 MB
  __bf16* kfT   = (__bf16*)(ws + 134217728);        // 64 MB
  __bf16* vT    = (__bf16*)(ws + 201326592);        // 64 MB
  __bf16* Wqkvb = (__bf16*)(ws + 268435456);        // 6 MB
  __bf16* Wob   = (__bf16*)(ws + 274726912);        // 2 MB
  __bf16* attnb = xb;                               // alias: xb dead after QKV GEMM

  cvt_kernel<<<4096, 256, 0, stream>>>(x, xb, (MROWS * DMODEL) / 4);
  cvt_kernel<<<1024, 256, 0, stream>>>(Wq, Wqkvb,                 (DMODEL * DMODEL) / 4);
  cvt_kernel<<<1024, 256, 0, stream>>>(Wk, Wqkvb + DMODEL * DMODEL,     (DMODEL * DMODEL) / 4);
  cvt_kernel<<<1024, 256, 0, stream>>>(Wv, Wqkvb + 2 * DMODEL * DMODEL, (DMODEL * DMODEL) / 4);
  cvt_kernel<<<1024, 256, 0, stream>>>(Wo, Wob, (DMODEL * DMODEL) / 4);

  gemm256_kernel<0><<<1536, 512, 131072, stream>>>(xb, Wqkvb, bq, bk, bv,
                                                   qf, kfT, vT, nullptr);
  attn_kernel<<<NBATCH * NHEAD, 256, 0, stream>>>(qf, kfT, vT, attnb);
  gemm256_kernel<1><<<512, 512, 131072, stream>>>(attnb, Wob, bo, nullptr, nullptr,
                                                  nullptr, nullptr, nullptr, out);
}

// Round 3
// 437.697 us; speedup vs baseline: 1.1615x; 1.0303x over previous
//
#include <hip/hip_runtime.h>
#include <hip/hip_bf16.h>

typedef __attribute__((ext_vector_type(8))) __bf16 bf16x8;
typedef __attribute__((ext_vector_type(4))) __bf16 bf16x4;
typedef __attribute__((ext_vector_type(4))) float f32x4;

#define NBATCH 64
#define NSEQ   512
#define DMODEL 1024
#define NHEAD  16
#define DHEAD  64
#define MROWS  (NBATCH * NSEQ)   // 32768

static __device__ __forceinline__ void gload_lds16(const void* gp, void* lp) {
  __builtin_amdgcn_global_load_lds(
      (__attribute__((address_space(1))) const void*)gp,
      (__attribute__((address_space(3))) void*)lp,
      16, 0, 0);
}

// ---------------------------------------------------------------- merged convert
// virtual float4 index space: [0, 8388608) -> x, then 4x 262144 -> Wq,Wk,Wv,Wo
__global__ void cvt_all_kernel(const float* __restrict__ x, const float* __restrict__ Wq,
                               const float* __restrict__ Wk, const float* __restrict__ Wv,
                               const float* __restrict__ Wo,
                               __bf16* __restrict__ xb, __bf16* __restrict__ Wqkvb,
                               __bf16* __restrict__ Wob) {
  constexpr int NX = (MROWS * DMODEL) / 4;          // 8388608
  constexpr int NW = (DMODEL * DMODEL) / 4;         // 262144
  int i = blockIdx.x * blockDim.x + threadIdx.x;
  const int stride = gridDim.x * blockDim.x;
  for (; i < NX + 4 * NW; i += stride) {
    const float* src; __bf16* dst; int idx;
    if (i < NX)            { src = x;  dst = xb;             idx = i; }
    else if (i < NX + NW)  { src = Wq; dst = Wqkvb;          idx = i - NX; }
    else if (i < NX + 2*NW){ src = Wk; dst = Wqkvb + 4*NW;   idx = i - NX - NW; }
    else if (i < NX + 3*NW){ src = Wv; dst = Wqkvb + 8*NW;   idx = i - NX - 2*NW; }
    else                   { src = Wo; dst = Wob;            idx = i - NX - 3*NW; }
    const float4 v = reinterpret_cast<const float4*>(src)[idx];
    bf16x4 o;
    o.x = (__bf16)v.x; o.y = (__bf16)v.y; o.z = (__bf16)v.z; o.w = (__bf16)v.w;
    reinterpret_cast<bf16x4*>(dst)[idx] = o;
  }
}

// ---------------------------------------------------------------- 256x256 pipelined GEMM (NT)
// C[m,j] = sum_k A[m,k]*Bw[j,k], K=1024.
// Single barrier + single vmcnt(0) per K-tile; stages for T+1 (opposite buf) and
// ds_reads of tile T interleaved with MFMA quadrants in dependency order so the
// compiler's counted lgkmcnt gives read||MFMA overlap; waves drift within a tile.
// Safety: reads of T touch panels landed+visible at tile-top barrier; stages for
// T+1 write buf^1 whose reads completed before the PREVIOUS barrier.
template <int MODE>
__global__ __launch_bounds__(512, 1)
void gemm256_kernel(const __bf16* __restrict__ A, const __bf16* __restrict__ Bw,
                    const float* __restrict__ bias0, const float* __restrict__ bias1,
                    const float* __restrict__ bias2,
                    __bf16* __restrict__ outq, __bf16* __restrict__ outkT,
                    __bf16* __restrict__ outvT, float* __restrict__ outf) {
  extern __shared__ char smem[];
  constexpr int K = 1024;
  constexpr int NT = K / 64;                 // 16 K-tiles
  constexpr int NBN = (MODE == 0) ? 12 : 4;  // N/256
  constexpr int NWG = 128 * NBN;
  constexpr int CPX = NWG / 8;               // NWG % 8 == 0

  const int raw = blockIdx.x;
  const int wgid = (raw & 7) * CPX + (raw >> 3);   // XCD-chunked swizzle (T1)
  const int bm = wgid / NBN;
  const int bn = wgid - bm * NBN;
  const int m0 = bm * 256, j0 = bn * 256;

  const int tid = threadIdx.x;
  const int l = tid & 63;
  const int w = tid >> 6;
  const int wm = w >> 2, wn = w & 3;
  const int lrow = l & 15, g16 = l >> 4;

  f32x4 acc[8][4] = {};

  // stage one 16KB half-panel: part 0=A k0, 1=A k1, 2=B k0, 3=B k1
  auto stage = [&](int part, int tileIdx) {
    const int mat = part >> 1, kh = part & 1;
    const int buf = tileIdx & 1;
    char* region = smem + (((buf << 2) | (mat << 1) | kh) << 14);
    const __bf16* src = mat ? Bw : A;
    const int rowbase = mat ? j0 : m0;
    const int kk = tileIdx * 64 + kh * 32;
#pragma unroll
    for (int i = 0; i < 2; i++) {
      const int Q = i * 8192 + tid * 16;               // linear LDS dest byte
      const int Ls = Q ^ (((Q >> 7) & 3) << 4);        // inverse-swizzled logical byte
      gload_lds16(src + (size_t)(rowbase + (Ls >> 6)) * K + kk + ((Ls & 63) >> 1),
                  region + Q);
    }
  };

  auto ldfrag = [&](int mat, int kh, int buf, int row) -> bf16x8 {
    const int L = row * 64 + g16 * 16;
    const int phys = L ^ (((row >> 1) & 3) << 4);      // same involution as stage
    return *reinterpret_cast<const bf16x8*>(
        smem + (((buf << 2) | (mat << 1) | kh) << 14) + phys);
  };

  // ---- prologue: stage T0 fully, drain, sync
  stage(0, 0); stage(2, 0); stage(3, 0); stage(1, 0);
  asm volatile("s_waitcnt vmcnt(0)" ::: "memory");
  __builtin_amdgcn_s_barrier();

  const int arow = wm * 128 + lrow;
  const int brow = wn * 64 + lrow;

  for (int T = 0; T < NT; T++) {
    const int buf = T & 1;
    const bool pre = (T + 1 < NT);
    // next-tile k0 stages early (longest latency slack)
    if (pre) { stage(0, T + 1); stage(2, T + 1); }
    // reads for quadrants m0k0 / m1k0
    bf16x8 a0[4], b0[4], a1[4];
#pragma unroll
    for (int mi = 0; mi < 4; mi++) a0[mi] = ldfrag(0, 0, buf, arow + mi * 16);
#pragma unroll
    for (int ni = 0; ni < 4; ni++) b0[ni] = ldfrag(1, 0, buf, brow + ni * 16);
#pragma unroll
    for (int mi = 0; mi < 4; mi++) a1[mi] = ldfrag(0, 0, buf, arow + 64 + mi * 16);
    if (pre) { stage(3, T + 1); stage(1, T + 1); }
    __builtin_amdgcn_s_setprio(1);
#pragma unroll
    for (int mi = 0; mi < 4; mi++)
#pragma unroll
      for (int ni = 0; ni < 4; ni++)
        acc[mi][ni] = __builtin_amdgcn_mfma_f32_16x16x32_bf16(a0[mi], b0[ni], acc[mi][ni], 0, 0, 0);
    __builtin_amdgcn_s_setprio(0);
    // k1 A-half0 reads overlap m1k0 MFMA below
    bf16x8 a0n[4];
#pragma unroll
    for (int mi = 0; mi < 4; mi++) a0n[mi] = ldfrag(0, 1, buf, arow + mi * 16);
    __builtin_amdgcn_s_setprio(1);
#pragma unroll
    for (int mi = 0; mi < 4; mi++)
#pragma unroll
      for (int ni = 0; ni < 4; ni++)
        acc[4 + mi][ni] = __builtin_amdgcn_mfma_f32_16x16x32_bf16(a1[mi], b0[ni], acc[4 + mi][ni], 0, 0, 0);
    __builtin_amdgcn_s_setprio(0);
    // k1 B + A-half1 reads overlap m0k1 MFMA
    bf16x8 b1[4], a1n[4];
#pragma unroll
    for (int ni = 0; ni < 4; ni++) b1[ni] = ldfrag(1, 1, buf, brow + ni * 16);
#pragma unroll
    for (int mi = 0; mi < 4; mi++) a1n[mi] = ldfrag(0, 1, buf, arow + 64 + mi * 16);
    __builtin_amdgcn_s_setprio(1);
#pragma unroll
    for (int mi = 0; mi < 4; mi++)
#pragma unroll
      for (int ni = 0; ni < 4; ni++)
        acc[mi][ni] = __builtin_amdgcn_mfma_f32_16x16x32_bf16(a0n[mi], b1[ni], acc[mi][ni], 0, 0, 0);
#pragma unroll
    for (int mi = 0; mi < 4; mi++)
#pragma unroll
      for (int ni = 0; ni < 4; ni++)
        acc[4 + mi][ni] = __builtin_amdgcn_mfma_f32_16x16x32_bf16(a1n[mi], b1[ni], acc[4 + mi][ni], 0, 0, 0);
    __builtin_amdgcn_s_setprio(0);
    if (pre) {
      asm volatile("s_waitcnt vmcnt(0)" ::: "memory");
      __builtin_amdgcn_s_barrier();
    }
  }

  // ------------- epilogue (C frag: col = l&15, row = g16*4 + r) -------------
  if constexpr (MODE == 0) {
    const int sel = j0 >> 10;          // 0=q, 1=k, 2=v (256 | 1024 => never crosses)
    const int jb = j0 & 1023;
    const float* bias = (sel == 0) ? bias0 : ((sel == 1) ? bias1 : bias2);
    float bj[4];
#pragma unroll
    for (int ni = 0; ni < 4; ni++) bj[ni] = bias[jb + wn * 64 + ni * 16 + lrow];
    if (sel == 0) {
#pragma unroll
      for (int mi = 0; mi < 8; mi++) {
        const int mbase = m0 + wm * 128 + mi * 16 + g16 * 4;
#pragma unroll
        for (int r = 0; r < 4; r++) {
          const int m = mbase + r;
          const float dec = __expf(-(float)(m & (NSEQ - 1)) * (1.0f / NSEQ));
#pragma unroll
          for (int ni = 0; ni < 4; ni++) {
            const int j = jb + wn * 64 + ni * 16 + lrow;
            const float val = fmaxf(acc[mi][ni][r] + bj[ni], 0.f) * dec;
            outq[(size_t)m * DMODEL + j] = (__bf16)val;
          }
        }
      }
    } else {
#pragma unroll
      for (int mi = 0; mi < 8; mi++) {
        const int mbase = m0 + wm * 128 + mi * 16 + g16 * 4;
        const int bidx = mbase >> 9;
        const int n0 = mbase & (NSEQ - 1);
        float dec4[4];
        if (sel == 1) {
#pragma unroll
          for (int r = 0; r < 4; r++)
            dec4[r] = __expf(-(float)(n0 + r) * (1.0f / NSEQ));
        }
        __bf16* dst = (sel == 1) ? outkT : outvT;
#pragma unroll
        for (int ni = 0; ni < 4; ni++) {
          const int j = jb + wn * 64 + ni * 16 + lrow;
          bf16x4 pk;
#pragma unroll
          for (int r = 0; r < 4; r++) {
            float val = acc[mi][ni][r] + bj[ni];
            if (sel == 1) val = fmaxf(val, 0.f) * dec4[r];
            pk[r] = (__bf16)val;
          }
          *reinterpret_cast<bf16x4*>(
              &dst[((size_t)((bidx * NHEAD + (j >> 6)) * DHEAD + (j & 63))) * NSEQ + n0]) = pk;
        }
      }
    }
  } else {
#pragma unroll
    for (int mi = 0; mi < 8; mi++) {
      const int mbase = m0 + wm * 128 + mi * 16 + g16 * 4;
#pragma unroll
      for (int ni = 0; ni < 4; ni++) {
        const int j = j0 + wn * 64 + ni * 16 + lrow;
        const float bo = bias0[j];
#pragma unroll
        for (int r = 0; r < 4; r++)
          outf[(size_t)(mbase + r) * DMODEL + j] = acc[mi][ni][r] + bo;
      }
    }
  }
}

// ---------------------------------------------------------------- attention core
// one block per (b,h); 256 threads = 4 waves.
__global__ void attn_kernel(const __bf16* __restrict__ qf, const __bf16* __restrict__ kfT,
                            const __bf16* __restrict__ vT, __bf16* __restrict__ attn) {
  const int bh = blockIdx.x;                 // b*16 + h
  const int b = bh >> 4, h = bh & 15;
  const __bf16* kT = kfT + (size_t)bh * DHEAD * NSEQ;
  const __bf16* vTp = vT + (size_t)bh * DHEAD * NSEQ;
  const __bf16* qp = qf + (size_t)b * NSEQ * DMODEL + h * DHEAD;
  __bf16* op = attn + (size_t)b * NSEQ * DMODEL + h * DHEAD;

  const int tid = threadIdx.x;
  const int l = tid & 63;
  const int w = tid >> 6;
  const int lrow = l & 15, lk = (l >> 4) * 8;

  __shared__ __bf16 KVT[64][88];
  __shared__ float Ksum[64];
  __shared__ float ksum_part[4][64];
  __shared__ float denom[512];

  // ---- KV[d,e] = sum_n kfT[d,n]*vT[e,n]; wave w owns d in [w*16, w*16+16)
  {
    f32x4 kv[4] = {};
    const int arow = w * 16 + lrow;
    for (int kk = 0; kk < NSEQ; kk += 32) {
      bf16x8 a = *reinterpret_cast<const bf16x8*>(&kT[(size_t)arow * NSEQ + kk + lk]);
#pragma unroll
      for (int ni = 0; ni < 4; ni++) {
        bf16x8 bv = *reinterpret_cast<const bf16x8*>(&vTp[(size_t)(ni * 16 + lrow) * NSEQ + kk + lk]);
        kv[ni] = __builtin_amdgcn_mfma_f32_16x16x32_bf16(a, bv, kv[ni], 0, 0, 0);
      }
    }
    const int d0 = w * 16 + ((l >> 4) << 2);
#pragma unroll
    for (int ni = 0; ni < 4; ni++) {
      const int e = ni * 16 + lrow;
      bf16x4 pk;
#pragma unroll
      for (int r = 0; r < 4; r++) pk[r] = (__bf16)kv[ni][r];
      *reinterpret_cast<bf16x4*>(&KVT[e][d0]) = pk;
    }
  }

  // ---- Ksum[d] = sum_n kfT[d,n]
  {
    const int d = tid & 63, part = tid >> 6;
    float s = 0.f;
    for (int n = part * 128; n < part * 128 + 128; n += 8) {
      bf16x8 kv8 = *reinterpret_cast<const bf16x8*>(&kT[(size_t)d * NSEQ + n]);
#pragma unroll
      for (int j = 0; j < 8; j++) s += (float)kv8[j];
    }
    ksum_part[part][d] = s;
  }
  __syncthreads();
  if (tid < 64)
    Ksum[tid] = ksum_part[0][tid] + ksum_part[1][tid] + ksum_part[2][tid] + ksum_part[3][tid];
  __syncthreads();

  // ---- denom[n] = qf[n,:] . Ksum + eps
  for (int n = tid; n < NSEQ; n += 256) {
    float s = 0.f;
#pragma unroll
    for (int d = 0; d < DHEAD; d += 8) {
      bf16x8 q8 = *reinterpret_cast<const bf16x8*>(&qp[(size_t)n * DMODEL + d]);
#pragma unroll
      for (int j = 0; j < 8; j++) s += (float)q8[j] * Ksum[d + j];
    }
    denom[n] = s + 1e-6f;
  }
  __syncthreads();

  // ---- out[n,e] = (sum_d qf[n,d]*KVT[e,d]) / denom[n]
  for (int t = 0; t < 8; t++) {
    const int nrow = t * 64 + w * 16 + lrow;
    bf16x8 a0 = *reinterpret_cast<const bf16x8*>(&qp[(size_t)nrow * DMODEL + lk]);
    bf16x8 a1 = *reinterpret_cast<const bf16x8*>(&qp[(size_t)nrow * DMODEL + 32 + lk]);
    f32x4 o[4] = {};
#pragma unroll
    for (int ni = 0; ni < 4; ni++) {
      bf16x8 b0 = *reinterpret_cast<const bf16x8*>(&KVT[ni * 16 + lrow][lk]);
      bf16x8 b1 = *reinterpret_cast<const bf16x8*>(&KVT[ni * 16 + lrow][32 + lk]);
      o[ni] = __builtin_amdgcn_mfma_f32_16x16x32_bf16(a0, b0, o[ni], 0, 0, 0);
      o[ni] = __builtin_amdgcn_mfma_f32_16x16x32_bf16(a1, b1, o[ni], 0, 0, 0);
    }
    const int n0 = t * 64 + w * 16 + ((l >> 4) << 2);
#pragma unroll
    for (int ni = 0; ni < 4; ni++) {
      const int e = ni * 16 + lrow;
#pragma unroll
      for (int r = 0; r < 4; r++)
        op[(size_t)(n0 + r) * DMODEL + e] = (__bf16)(o[ni][r] / denom[n0 + r]);
    }
  }
}

// ---------------------------------------------------------------- launch
extern "C" void kernel_launch(void* const* d_in, const int* in_sizes, int n_in,
                              void* d_out, int out_size, void* d_ws, size_t ws_size,
                              hipStream_t stream) {
  (void)in_sizes; (void)n_in; (void)out_size; (void)ws_size;
  const float* x  = (const float*)d_in[0];
  const float* Wq = (const float*)d_in[1];
  const float* bq = (const float*)d_in[2];
  const float* Wk = (const float*)d_in[3];
  const float* bk = (const float*)d_in[4];
  const float* Wv = (const float*)d_in[5];
  const float* bv = (const float*)d_in[6];
  const float* Wo = (const float*)d_in[7];
  const float* bo = (const float*)d_in[8];
  float* out = (float*)d_out;

  char* ws = (char*)d_ws;
  __bf16* xb    = (__bf16*)(ws);                    // 64 MB  (reused as attn output)
  __bf16* qf    = (__bf16*)(ws + 67108864);         // 64 MB
  __bf16* kfT   = (__bf16*)(ws + 134217728);        // 64 MB
  __bf16* vT    = (__bf16*)(ws + 201326592);        // 64 MB
  __bf16* Wqkvb = (__bf16*)(ws + 268435456);        // 6 MB
  __bf16* Wob   = (__bf16*)(ws + 274726912);        // 2 MB
  __bf16* attnb = xb;                               // alias: xb dead after QKV GEMM

  cvt_all_kernel<<<4096, 256, 0, stream>>>(x, Wq, Wk, Wv, Wo, xb, Wqkvb, Wob);

  gemm256_kernel<0><<<1536, 512, 131072, stream>>>(xb, Wqkvb, bq, bk, bv,
                                                   qf, kfT, vT, nullptr);
  attn_kernel<<<NBATCH * NHEAD, 256, 0, stream>>>(qf, kfT, vT, attnb);
  gemm256_kernel<1><<<512, 512, 131072, stream>>>(attnb, Wob, bo, nullptr, nullptr,
                                                  nullptr, nullptr, nullptr, out);
}

// Round 4
// 436.608 us; speedup vs baseline: 1.1644x; 1.0025x over previous
//
#include <hip/hip_runtime.h>
#include <hip/hip_bf16.h>

typedef __attribute__((ext_vector_type(8))) __bf16 bf16x8;
typedef __attribute__((ext_vector_type(4))) __bf16 bf16x4;
typedef __attribute__((ext_vector_type(4))) float f32x4;

#define NBATCH 64
#define NSEQ   512
#define DMODEL 1024
#define NHEAD  16
#define DHEAD  64
#define MROWS  (NBATCH * NSEQ)   // 32768

static __device__ __forceinline__ void gload_lds16(const void* gp, void* lp) {
  __builtin_amdgcn_global_load_lds(
      (__attribute__((address_space(1))) const void*)gp,
      (__attribute__((address_space(3))) void*)lp,
      16, 0, 0);
}

// ---------------------------------------------------------------- merged convert
__global__ void cvt_all_kernel(const float* __restrict__ x, const float* __restrict__ Wq,
                               const float* __restrict__ Wk, const float* __restrict__ Wv,
                               const float* __restrict__ Wo,
                               __bf16* __restrict__ xb, __bf16* __restrict__ Wqkvb,
                               __bf16* __restrict__ Wob) {
  constexpr int NX = (MROWS * DMODEL) / 4;          // 8388608
  constexpr int NW = (DMODEL * DMODEL) / 4;         // 262144
  int i = blockIdx.x * blockDim.x + threadIdx.x;
  const int stride = gridDim.x * blockDim.x;
  for (; i < NX + 4 * NW; i += stride) {
    const float* src; __bf16* dst; int idx;
    if (i < NX)            { src = x;  dst = xb;             idx = i; }
    else if (i < NX + NW)  { src = Wq; dst = Wqkvb;          idx = i - NX; }
    else if (i < NX + 2*NW){ src = Wk; dst = Wqkvb + 4*NW;   idx = i - NX - NW; }
    else if (i < NX + 3*NW){ src = Wv; dst = Wqkvb + 8*NW;   idx = i - NX - 2*NW; }
    else                   { src = Wo; dst = Wob;            idx = i - NX - 3*NW; }
    const float4 v = reinterpret_cast<const float4*>(src)[idx];
    bf16x4 o;
    o.x = (__bf16)v.x; o.y = (__bf16)v.y; o.z = (__bf16)v.z; o.w = (__bf16)v.w;
    reinterpret_cast<bf16x4*>(dst)[idx] = o;
  }
}

// ---------------------------------------------------------------- 256x256 8-phase GEMM (NT)
// Faithful m201-style schedule: 4 phases per K-tile, each phase =
//   { ds_reads ; stage 1 panel (2 gloads) ; barrier ; lgkmcnt(0) ;
//     setprio(1) ; 16 MFMA ; setprio(0) ; barrier }
// Counted vmcnt(4) once per K-tile (vmcnt(0) only at tile NT-2).
// Staging ledger (verified): P1 stages A-k1(T+1), P2 B-k1(T+1) [buf^1, freed at
// P4 of T-1]; P3 stages A-k0(T+2) [same buf, last read at P2], P4 B-k0(T+2)
// [last read P1]. Steady state: 12 loads outstanding at tile end, keep 4
// ({A,B}-k0(T+2)); every panel forced-drained one tile boundary before use.
template <int MODE>
__global__ __launch_bounds__(512, 1)
void gemm256_kernel(const __bf16* __restrict__ A, const __bf16* __restrict__ Bw,
                    const float* __restrict__ bias0, const float* __restrict__ bias1,
                    const float* __restrict__ bias2,
                    __bf16* __restrict__ outq, __bf16* __restrict__ outkT,
                    __bf16* __restrict__ outvT, float* __restrict__ outf) {
  extern __shared__ char smem[];
  constexpr int K = 1024;
  constexpr int NT = K / 64;                 // 16 K-tiles
  constexpr int NBN = (MODE == 0) ? 12 : 4;  // N/256
  constexpr int NWG = 128 * NBN;
  constexpr int CPX = NWG / 8;               // NWG % 8 == 0

  const int raw = blockIdx.x;
  const int wgid = (raw & 7) * CPX + (raw >> 3);   // XCD-chunked swizzle (T1)
  const int bm = wgid / NBN;
  const int bn = wgid - bm * NBN;
  const int m0 = bm * 256, j0 = bn * 256;

  const int tid = threadIdx.x;
  const int l = tid & 63;
  const int w = tid >> 6;
  const int wm = w >> 2, wn = w & 3;
  const int lrow = l & 15, g16 = l >> 4;

  f32x4 acc[8][4] = {};

  // stage one 16KB panel half (2 gloads/thread): mat 0=A 1=B, kh 0/1
  auto stage2 = [&](int mat, int kh, int tileIdx) {
    const int buf = tileIdx & 1;
    char* region = smem + (((buf << 2) | (mat << 1) | kh) << 14);
    const __bf16* src = mat ? Bw : A;
    const int rowbase = mat ? j0 : m0;
    const int kk = tileIdx * 64 + kh * 32;
#pragma unroll
    for (int i = 0; i < 2; i++) {
      const int Q = i * 8192 + tid * 16;               // linear LDS dest byte
      const int Ls = Q ^ (((Q >> 7) & 3) << 4);        // inverse-swizzled logical byte
      gload_lds16(src + (size_t)(rowbase + (Ls >> 6)) * K + kk + ((Ls & 63) >> 1),
                  region + Q);
    }
  };

  auto ldfrag = [&](int mat, int kh, int buf, int row) -> bf16x8 {
    const int L = row * 64 + g16 * 16;
    const int phys = L ^ (((row >> 1) & 3) << 4);      // same involution as stage
    return *reinterpret_cast<const bf16x8*>(
        smem + (((buf << 2) | (mat << 1) | kh) << 14) + phys);
  };

  // ---- prologue: tile0 fully + {A,B}-k0 of tile1; force tile0, keep 4 in flight
  stage2(0, 0, 0); stage2(1, 0, 0); stage2(0, 1, 0); stage2(1, 1, 0);
  stage2(0, 0, 1); stage2(1, 0, 1);
  asm volatile("s_waitcnt vmcnt(4)" ::: "memory");
  __builtin_amdgcn_s_barrier();

  const int arow = wm * 128 + lrow;
  const int brow = wn * 64 + lrow;

  auto tile = [&](int T, int buf) {
    // ---------------- P1: reads a0,b0 (8) | stage A-k1(T+1) ----------------
    bf16x8 a0[4], b0[4];
#pragma unroll
    for (int mi = 0; mi < 4; mi++) a0[mi] = ldfrag(0, 0, buf, arow + mi * 16);
#pragma unroll
    for (int ni = 0; ni < 4; ni++) b0[ni] = ldfrag(1, 0, buf, brow + ni * 16);
    if (T + 1 < NT) stage2(0, 1, T + 1);
    asm volatile("" ::: "memory");
    __builtin_amdgcn_s_barrier();
    asm volatile("s_waitcnt lgkmcnt(0)" ::: "memory");
    __builtin_amdgcn_s_setprio(1);
#pragma unroll
    for (int mi = 0; mi < 4; mi++)
#pragma unroll
      for (int ni = 0; ni < 4; ni++)
        acc[mi][ni] = __builtin_amdgcn_mfma_f32_16x16x32_bf16(a0[mi], b0[ni], acc[mi][ni], 0, 0, 0);
    __builtin_amdgcn_s_setprio(0);
    asm volatile("" ::: "memory");
    __builtin_amdgcn_s_barrier();
    // ---------------- P2: reads a1 (4) | stage B-k1(T+1) ----------------
    bf16x8 a1[4];
#pragma unroll
    for (int mi = 0; mi < 4; mi++) a1[mi] = ldfrag(0, 0, buf, arow + 64 + mi * 16);
    if (T + 1 < NT) stage2(1, 1, T + 1);
    asm volatile("" ::: "memory");
    __builtin_amdgcn_s_barrier();
    asm volatile("s_waitcnt lgkmcnt(0)" ::: "memory");
    __builtin_amdgcn_s_setprio(1);
#pragma unroll
    for (int mi = 0; mi < 4; mi++)
#pragma unroll
      for (int ni = 0; ni < 4; ni++)
        acc[4 + mi][ni] = __builtin_amdgcn_mfma_f32_16x16x32_bf16(a1[mi], b0[ni], acc[4 + mi][ni], 0, 0, 0);
    __builtin_amdgcn_s_setprio(0);
    asm volatile("" ::: "memory");
    __builtin_amdgcn_s_barrier();
    // ---------------- P3: reads a2,b1 (8) | stage A-k0(T+2) ----------------
    bf16x8 a2[4], b1[4];
#pragma unroll
    for (int mi = 0; mi < 4; mi++) a2[mi] = ldfrag(0, 1, buf, arow + mi * 16);
#pragma unroll
    for (int ni = 0; ni < 4; ni++) b1[ni] = ldfrag(1, 1, buf, brow + ni * 16);
    if (T + 2 < NT) stage2(0, 0, T + 2);
    asm volatile("" ::: "memory");
    __builtin_amdgcn_s_barrier();
    asm volatile("s_waitcnt lgkmcnt(0)" ::: "memory");
    __builtin_amdgcn_s_setprio(1);
#pragma unroll
    for (int mi = 0; mi < 4; mi++)
#pragma unroll
      for (int ni = 0; ni < 4; ni++)
        acc[mi][ni] = __builtin_amdgcn_mfma_f32_16x16x32_bf16(a2[mi], b1[ni], acc[mi][ni], 0, 0, 0);
    __builtin_amdgcn_s_setprio(0);
    asm volatile("" ::: "memory");
    __builtin_amdgcn_s_barrier();
    // ---------------- P4: reads a3 (4) | stage B-k0(T+2) ----------------
    bf16x8 a3[4];
#pragma unroll
    for (int mi = 0; mi < 4; mi++) a3[mi] = ldfrag(0, 1, buf, arow + 64 + mi * 16);
    if (T + 2 < NT) stage2(1, 0, T + 2);
    asm volatile("" ::: "memory");
    __builtin_amdgcn_s_barrier();
    asm volatile("s_waitcnt lgkmcnt(0)" ::: "memory");
    __builtin_amdgcn_s_setprio(1);
#pragma unroll
    for (int mi = 0; mi < 4; mi++)
#pragma unroll
      for (int ni = 0; ni < 4; ni++)
        acc[4 + mi][ni] = __builtin_amdgcn_mfma_f32_16x16x32_bf16(a3[mi], b1[ni], acc[4 + mi][ni], 0, 0, 0);
    __builtin_amdgcn_s_setprio(0);
    if (T < NT - 1) {
      if (T < NT - 2)  asm volatile("s_waitcnt vmcnt(4)" ::: "memory");
      else             asm volatile("s_waitcnt vmcnt(0)" ::: "memory");
      __builtin_amdgcn_s_barrier();
    }
  };

  for (int Tb = 0; Tb < NT; Tb += 2) { tile(Tb, 0); tile(Tb + 1, 1); }

  // ------------- epilogue (C frag: col = l&15, row = g16*4 + r) -------------
  if constexpr (MODE == 0) {
    const int sel = j0 >> 10;          // 0=q, 1=k, 2=v (256 | 1024 => never crosses)
    const int jb = j0 & 1023;
    const float* bias = (sel == 0) ? bias0 : ((sel == 1) ? bias1 : bias2);
    float bj[4];
#pragma unroll
    for (int ni = 0; ni < 4; ni++) bj[ni] = bias[jb + wn * 64 + ni * 16 + lrow];
    if (sel == 0) {
#pragma unroll
      for (int mi = 0; mi < 8; mi++) {
        const int mbase = m0 + wm * 128 + mi * 16 + g16 * 4;
#pragma unroll
        for (int r = 0; r < 4; r++) {
          const int m = mbase + r;
          const float dec = __expf(-(float)(m & (NSEQ - 1)) * (1.0f / NSEQ));
#pragma unroll
          for (int ni = 0; ni < 4; ni++) {
            const int j = jb + wn * 64 + ni * 16 + lrow;
            const float val = fmaxf(acc[mi][ni][r] + bj[ni], 0.f) * dec;
            outq[(size_t)m * DMODEL + j] = (__bf16)val;
          }
        }
      }
    } else {
#pragma unroll
      for (int mi = 0; mi < 8; mi++) {
        const int mbase = m0 + wm * 128 + mi * 16 + g16 * 4;
        const int bidx = mbase >> 9;
        const int n0 = mbase & (NSEQ - 1);
        float dec4[4];
        if (sel == 1) {
#pragma unroll
          for (int r = 0; r < 4; r++)
            dec4[r] = __expf(-(float)(n0 + r) * (1.0f / NSEQ));
        }
        __bf16* dst = (sel == 1) ? outkT : outvT;
#pragma unroll
        for (int ni = 0; ni < 4; ni++) {
          const int j = jb + wn * 64 + ni * 16 + lrow;
          bf16x4 pk;
#pragma unroll
          for (int r = 0; r < 4; r++) {
            float val = acc[mi][ni][r] + bj[ni];
            if (sel == 1) val = fmaxf(val, 0.f) * dec4[r];
            pk[r] = (__bf16)val;
          }
          *reinterpret_cast<bf16x4*>(
              &dst[((size_t)((bidx * NHEAD + (j >> 6)) * DHEAD + (j & 63))) * NSEQ + n0]) = pk;
        }
      }
    }
  } else {
#pragma unroll
    for (int mi = 0; mi < 8; mi++) {
      const int mbase = m0 + wm * 128 + mi * 16 + g16 * 4;
#pragma unroll
      for (int ni = 0; ni < 4; ni++) {
        const int j = j0 + wn * 64 + ni * 16 + lrow;
        const float bo = bias0[j];
#pragma unroll
        for (int r = 0; r < 4; r++)
          outf[(size_t)(mbase + r) * DMODEL + j] = acc[mi][ni][r] + bo;
      }
    }
  }
}

// ---------------------------------------------------------------- attention core
// one block per (b,h); 256 threads = 4 waves.
__global__ void attn_kernel(const __bf16* __restrict__ qf, const __bf16* __restrict__ kfT,
                            const __bf16* __restrict__ vT, __bf16* __restrict__ attn) {
  const int bh = blockIdx.x;                 // b*16 + h
  const int b = bh >> 4, h = bh & 15;
  const __bf16* kT = kfT + (size_t)bh * DHEAD * NSEQ;
  const __bf16* vTp = vT + (size_t)bh * DHEAD * NSEQ;
  const __bf16* qp = qf + (size_t)b * NSEQ * DMODEL + h * DHEAD;
  __bf16* op = attn + (size_t)b * NSEQ * DMODEL + h * DHEAD;

  const int tid = threadIdx.x;
  const int l = tid & 63;
  const int w = tid >> 6;
  const int lrow = l & 15, lk = (l >> 4) * 8;

  __shared__ __bf16 KVT[64][88];
  __shared__ float Ksum[64];
  __shared__ float ksum_part[4][64];
  __shared__ float denom[512];

  // ---- KV[d,e] = sum_n kfT[d,n]*vT[e,n]; wave w owns d in [w*16, w*16+16)
  {
    f32x4 kv[4] = {};
    const int arow = w * 16 + lrow;
    for (int kk = 0; kk < NSEQ; kk += 32) {
      bf16x8 a = *reinterpret_cast<const bf16x8*>(&kT[(size_t)arow * NSEQ + kk + lk]);
#pragma unroll
      for (int ni = 0; ni < 4; ni++) {
        bf16x8 bv = *reinterpret_cast<const bf16x8*>(&vTp[(size_t)(ni * 16 + lrow) * NSEQ + kk + lk]);
        kv[ni] = __builtin_amdgcn_mfma_f32_16x16x32_bf16(a, bv, kv[ni], 0, 0, 0);
      }
    }
    const int d0 = w * 16 + ((l >> 4) << 2);
#pragma unroll
    for (int ni = 0; ni < 4; ni++) {
      const int e = ni * 16 + lrow;
      bf16x4 pk;
#pragma unroll
      for (int r = 0; r < 4; r++) pk[r] = (__bf16)kv[ni][r];
      *reinterpret_cast<bf16x4*>(&KVT[e][d0]) = pk;
    }
  }

  // ---- Ksum[d] = sum_n kfT[d,n]
  {
    const int d = tid & 63, part = tid >> 6;
    float s = 0.f;
    for (int n = part * 128; n < part * 128 + 128; n += 8) {
      bf16x8 kv8 = *reinterpret_cast<const bf16x8*>(&kT[(size_t)d * NSEQ + n]);
#pragma unroll
      for (int j = 0; j < 8; j++) s += (float)kv8[j];
    }
    ksum_part[part][d] = s;
  }
  __syncthreads();
  if (tid < 64)
    Ksum[tid] = ksum_part[0][tid] + ksum_part[1][tid] + ksum_part[2][tid] + ksum_part[3][tid];
  __syncthreads();

  // ---- denom[n] = qf[n,:] . Ksum + eps
  for (int n = tid; n < NSEQ; n += 256) {
    float s = 0.f;
#pragma unroll
    for (int d = 0; d < DHEAD; d += 8) {
      bf16x8 q8 = *reinterpret_cast<const bf16x8*>(&qp[(size_t)n * DMODEL + d]);
#pragma unroll
      for (int j = 0; j < 8; j++) s += (float)q8[j] * Ksum[d + j];
    }
    denom[n] = s + 1e-6f;
  }
  __syncthreads();

  // ---- out[n,e] = (sum_d qf[n,d]*KVT[e,d]) / denom[n]
  for (int t = 0; t < 8; t++) {
    const int nrow = t * 64 + w * 16 + lrow;
    bf16x8 a0 = *reinterpret_cast<const bf16x8*>(&qp[(size_t)nrow * DMODEL + lk]);
    bf16x8 a1 = *reinterpret_cast<const bf16x8*>(&qp[(size_t)nrow * DMODEL + 32 + lk]);
    f32x4 o[4] = {};
#pragma unroll
    for (int ni = 0; ni < 4; ni++) {
      bf16x8 b0 = *reinterpret_cast<const bf16x8*>(&KVT[ni * 16 + lrow][lk]);
      bf16x8 b1 = *reinterpret_cast<const bf16x8*>(&KVT[ni * 16 + lrow][32 + lk]);
      o[ni] = __builtin_amdgcn_mfma_f32_16x16x32_bf16(a0, b0, o[ni], 0, 0, 0);
      o[ni] = __builtin_amdgcn_mfma_f32_16x16x32_bf16(a1, b1, o[ni], 0, 0, 0);
    }
    const int n0 = t * 64 + w * 16 + ((l >> 4) << 2);
#pragma unroll
    for (int ni = 0; ni < 4; ni++) {
      const int e = ni * 16 + lrow;
#pragma unroll
      for (int r = 0; r < 4; r++)
        op[(size_t)(n0 + r) * DMODEL + e] = (__bf16)(o[ni][r] / denom[n0 + r]);
    }
  }
}

// ---------------------------------------------------------------- launch
extern "C" void kernel_launch(void* const* d_in, const int* in_sizes, int n_in,
                              void* d_out, int out_size, void* d_ws, size_t ws_size,
                              hipStream_t stream) {
  (void)in_sizes; (void)n_in; (void)out_size; (void)ws_size;
  const float* x  = (const float*)d_in[0];
  const float* Wq = (const float*)d_in[1];
  const float* bq = (const float*)d_in[2];
  const float* Wk = (const float*)d_in[3];
  const float* bk = (const float*)d_in[4];
  const float* Wv = (const float*)d_in[5];
  const float* bv = (const float*)d_in[6];
  const float* Wo = (const float*)d_in[7];
  const float* bo = (const float*)d_in[8];
  float* out = (float*)d_out;

  char* ws = (char*)d_ws;
  __bf16* xb    = (__bf16*)(ws);                    // 64 MB  (reused as attn output)
  __bf16* qf    = (__bf16*)(ws + 67108864);         // 64 MB
  __bf16* kfT   = (__bf16*)(ws + 134217728);        // 64 MB
  __bf16* vT    = (__bf16*)(ws + 201326592);        // 64 MB
  __bf16* Wqkvb = (__bf16*)(ws + 268435456);        // 6 MB
  __bf16* Wob   = (__bf16*)(ws + 274726912);        // 2 MB
  __bf16* attnb = xb;                               // alias: xb dead after QKV GEMM

  cvt_all_kernel<<<4096, 256, 0, stream>>>(x, Wq, Wk, Wv, Wo, xb, Wqkvb, Wob);

  gemm256_kernel<0><<<1536, 512, 131072, stream>>>(xb, Wqkvb, bq, bk, bv,
                                                   qf, kfT, vT, nullptr);
  attn_kernel<<<NBATCH * NHEAD, 256, 0, stream>>>(qf, kfT, vT, attnb);
  gemm256_kernel<1><<<512, 512, 131072, stream>>>(attnb, Wob, bo, nullptr, nullptr,
                                                  nullptr, nullptr, nullptr, out);
}